// Round 4
// baseline (966.874 us; speedup 1.0000x reference)
//
#include <hip/hip_runtime.h>

#define BT 256
#define HID 2048
#define NE 8
#define INTER 4096

typedef short short8 __attribute__((ext_vector_type(8)));
typedef float f32x4 __attribute__((ext_vector_type(4)));

__device__ inline unsigned short f2bf(float f){
  unsigned int u = __float_as_uint(f);
  u += 0x7fff + ((u >> 16) & 1);   // RNE
  return (unsigned short)(u >> 16);
}
__device__ inline ushort4 f2bf4(float4 v){
  ushort4 b; b.x=f2bf(v.x); b.y=f2bf(v.y); b.z=f2bf(v.z); b.w=f2bf(v.w); return b;
}
__device__ inline unsigned int pk2(float x, float y){
  return (unsigned int)f2bf(x) | ((unsigned int)f2bf(y) << 16);
}
__device__ inline short8 cvt8(float4 a, float4 b){
  union { unsigned int u[4]; short8 s; } r;
  r.u[0] = pk2(a.x, a.y); r.u[1] = pk2(a.z, a.w);
  r.u[2] = pk2(b.x, b.y); r.u[3] = pk2(b.z, b.w);
  return r.s;
}

// async 16B global->LDS DMA (wave-uniform base + lane*16; our fills are lane-contiguous)
__device__ inline void glds16(const void* g, void* l){
  __builtin_amdgcn_global_load_lds(
      (const __attribute__((address_space(1))) unsigned int*)g,
      (__attribute__((address_space(3))) unsigned int*)l, 16, 0, 0);
}

// fine-grained pipeline barriers: NEVER drain vmcnt to 0 mid-loop.
// single asm so the compiler cannot insert its own waitcnt between wait and barrier.
#define WAIT_BARRIER(N) asm volatile("s_waitcnt vmcnt(" #N ")\n\ts_barrier" ::: "memory")
#define RAW_BARRIER()   asm volatile("s_barrier" ::: "memory")

// ---------------- routing: per-expert token lists (last-write-wins on dup) ----------------
__global__ void routing_kernel(const int* __restrict__ sel, const float* __restrict__ rw,
                               int* counts, int* bases, int* tokl, float* wtl){
  __shared__ int cnt[NE]; __shared__ int bs[NE]; __shared__ int cur[NE];
  int t = threadIdx.x;
  if (t < NE) cnt[t] = 0;
  __syncthreads();
  int s0 = sel[2*t], s1 = sel[2*t+1];
  float w0 = rw[2*t], w1 = rw[2*t+1];
  bool dup = (s0 == s1);
  atomicAdd(&cnt[s1], 1);
  if (!dup) atomicAdd(&cnt[s0], 1);
  __syncthreads();
  if (t == 0){ int a = 0; for (int e = 0; e < NE; e++){ bs[e] = a; cur[e] = a; a += cnt[e]; } }
  __syncthreads();
  int slot = atomicAdd(&cur[s1], 1); tokl[slot] = t; wtl[slot] = w1;
  if (!dup){ slot = atomicAdd(&cur[s0], 1); tokl[slot] = t; wtl[slot] = w0; }
  if (t < NE){ counts[t] = cnt[t]; bases[t] = bs[t]; }
}

// ---------------- gather: hsg[entry][k] = bf16(hs[tokl[entry]][k]) ----------------
__global__ void gather_kernel(const float* __restrict__ hs,
                              const int* __restrict__ counts, const int* __restrict__ bases,
                              const int* __restrict__ tokl, unsigned short* __restrict__ hsg){
  int b = blockIdx.x;
  int tot = bases[NE-1] + counts[NE-1];
  if (b >= tot) return;
  const float* src = hs + (size_t)tokl[b] * HID;
  unsigned short* dst = hsg + (size_t)b * HID;
  int t = threadIdx.x;
  float4 v0 = *(const float4*)(src + t*8);
  float4 v1 = *(const float4*)(src + t*8 + 4);
  *(ushort4*)(dst + t*8)     = f2bf4(v0);
  *(ushort4*)(dst + t*8 + 4) = f2bf4(v1);
}

// ---------------- gemm1: up/gate = hsg @ w13^T, cur = silu(up)*gate ----------------
// grid (INTER/64=64, 2, NE). Tile M=128, f-width 64 (=> 128 w13 rows up+gate), Ktile=32.
// LDS per buf: A 8KB bf16 + B 16KB fp32; dbuf = 48KB.
__global__ __launch_bounds__(256, 2) void gemm1_kernel(
    const unsigned short* __restrict__ hsg, const float* __restrict__ w13,
    const int* __restrict__ counts, const int* __restrict__ bases,
    unsigned short* __restrict__ cur)
{
  const int e = blockIdx.z;
  const int cnt = counts[e];
  const int mtile = blockIdx.y;
  if (mtile * 128 >= cnt) return;
  const int f0 = blockIdx.x * 64;
  const int base = bases[e];
  const int tid = threadIdx.x;

  __shared__ __align__(16) unsigned short Abuf[2][128*32];  // 2x8KB
  __shared__ __align__(16) float          Bbuf[2][128*32];  // 2x16KB

  // fill descriptors (lane-contiguous LDS offsets; XOR-swizzled global granules)
  const unsigned short* aG[2]; int aL[2];
#pragma unroll
  for (int r = 0; r < 2; r++){
    int off = r*4096 + tid*16;
    int row = off >> 6;                       // 64B bf16 rows
    int gpos = (off >> 4) & 3;
    int gglob = gpos ^ ((row >> 1) & 3);
    aG[r] = hsg + (size_t)(base + mtile*128 + row) * HID + gglob*8;
    aL[r] = off;
  }
  const float* bG[4]; int bL[4];
  const size_t ebase = (size_t)e * 2*INTER*HID;
#pragma unroll
  for (int r = 0; r < 4; r++){
    int off = r*4096 + tid*16;
    int row = off >> 7;                       // 128B fp32 rows
    int gpos = (off >> 4) & 7;
    int gglob = gpos ^ (row & 7);
    int wrow = (row < 64) ? (f0 + row) : (INTER + f0 + row - 64);
    bG[r] = w13 + ebase + (size_t)wrow * HID + gglob*4;
    bL[r] = off;
  }

  const int wv = tid >> 6, wm = wv >> 1, wn = wv & 1;
  const int lane = tid & 63;
  const int lrow = lane & 15, quad = lane >> 4;

  f32x4 acc[2][4][2];
#pragma unroll
  for (int s=0;s<2;s++) for (int mt=0;mt<4;mt++) for (int nt=0;nt<2;nt++)
    acc[s][mt][nt] = (f32x4){0.f,0.f,0.f,0.f};

  auto issue = [&](int t2, int p){
    int k0 = t2 * 32;
#pragma unroll
    for (int r = 0; r < 2; r++) glds16(aG[r] + k0, (char*)&Abuf[p][0] + aL[r]);
#pragma unroll
    for (int r = 0; r < 4; r++) glds16(bG[r] + k0, (char*)&Bbuf[p][0] + bL[r]);
  };
  auto compute = [&](int p){
    const unsigned short* A = &Abuf[p][0];
    const float* B = &Bbuf[p][0];
    short8 a[4], b[2][2];
#pragma unroll
    for (int mt = 0; mt < 4; mt++){
      int row = wm*64 + mt*16 + lrow;
      a[mt] = *(const short8*)(A + row*32 + ((quad ^ ((row>>1)&3)) * 8));
    }
#pragma unroll
    for (int s = 0; s < 2; s++)
#pragma unroll
      for (int nt = 0; nt < 2; nt++){
        int row = s*64 + wn*32 + nt*16 + lrow;
        int g0 = (2*quad) ^ (row & 7), g1 = (2*quad+1) ^ (row & 7);
        float4 x = *(const float4*)(B + row*32 + g0*4);
        float4 y = *(const float4*)(B + row*32 + g1*4);
        b[s][nt] = cvt8(x, y);
      }
#pragma unroll
    for (int s = 0; s < 2; s++)
#pragma unroll
      for (int mt = 0; mt < 4; mt++)
#pragma unroll
        for (int nt = 0; nt < 2; nt++)
          acc[s][mt][nt] = __builtin_amdgcn_mfma_f32_16x16x32_bf16(
              a[mt], b[s][nt], acc[s][mt][nt], 0,0,0);
  };

  const int T = HID / 32;   // 64
  issue(0, 0); issue(1, 1);
  for (int t = 0; t < T-1; t++){
    WAIT_BARRIER(6);        // tile t landed; tile t+1 still in flight
    compute(t & 1);
    RAW_BARRIER();          // all waves done reading buf (ds_reads already consumed by MFMA)
    if (t + 2 < T) issue(t + 2, t & 1);
  }
  WAIT_BARRIER(0);
  compute((T-1) & 1);

  // epilogue: silu(up)*gate -> bf16 cur (after vmcnt(0): safe for non-glds memory ops)
#pragma unroll
  for (int mt = 0; mt < 4; mt++){
#pragma unroll
    for (int reg = 0; reg < 4; reg++){
      int m = mtile*128 + wm*64 + mt*16 + quad*4 + reg;
      if (m >= cnt) continue;
      size_t rowoff = (size_t)(base + m) * INTER;
#pragma unroll
      for (int nt = 0; nt < 2; nt++){
        int i = f0 + wn*32 + nt*16 + lrow;
        float up   = acc[0][mt][nt][reg];
        float gate = acc[1][mt][nt][reg];
        float sv = up / (1.f + __expf(-up));
        cur[rowoff + i] = f2bf(sv * gate);
      }
    }
  }
}

// ---------------- gemm2: out += w * (cur @ w2^T) ----------------
// grid (HID/64=32, 2, NE). Tile M=128, H=64, Ktile=32, K=4096 -> 128 tiles.
// LDS per buf: A 8KB bf16 + B 8KB fp32; dbuf = 32KB.
__global__ __launch_bounds__(256, 2) void gemm2_kernel(
    const unsigned short* __restrict__ cur, const float* __restrict__ w2,
    const int* __restrict__ counts, const int* __restrict__ bases,
    const int* __restrict__ tokl, const float* __restrict__ wtl,
    float* __restrict__ out)
{
  const int e = blockIdx.z;
  const int cnt = counts[e];
  const int mtile = blockIdx.y;
  if (mtile * 128 >= cnt) return;
  const int h0 = blockIdx.x * 64;
  const int base = bases[e];
  const int tid = threadIdx.x;

  __shared__ __align__(16) unsigned short Abuf[2][128*32];  // 2x8KB
  __shared__ __align__(16) float          Bbuf[2][64*32];   // 2x8KB

  const unsigned short* aG[2]; int aL[2];
#pragma unroll
  for (int r = 0; r < 2; r++){
    int off = r*4096 + tid*16;
    int row = off >> 6;
    int gpos = (off >> 4) & 3;
    int gglob = gpos ^ ((row >> 1) & 3);
    aG[r] = cur + (size_t)(base + mtile*128 + row) * INTER + gglob*8;
    aL[r] = off;
  }
  const float* bG[2]; int bL[2];
  const size_t ebase = (size_t)e * HID * INTER;
#pragma unroll
  for (int r = 0; r < 2; r++){
    int off = r*4096 + tid*16;
    int row = off >> 7;
    int gpos = (off >> 4) & 7;
    int gglob = gpos ^ (row & 7);
    bG[r] = w2 + ebase + (size_t)(h0 + row) * INTER + gglob*4;
    bL[r] = off;
  }

  const int wv = tid >> 6, wm = wv >> 1, wn = wv & 1;
  const int lane = tid & 63;
  const int lrow = lane & 15, quad = lane >> 4;

  f32x4 acc[4][2];
#pragma unroll
  for (int mt=0;mt<4;mt++) for (int nt=0;nt<2;nt++)
    acc[mt][nt] = (f32x4){0.f,0.f,0.f,0.f};

  auto issue = [&](int t2, int p){
    int k0 = t2 * 32;
#pragma unroll
    for (int r = 0; r < 2; r++) glds16(aG[r] + k0, (char*)&Abuf[p][0] + aL[r]);
#pragma unroll
    for (int r = 0; r < 2; r++) glds16(bG[r] + k0, (char*)&Bbuf[p][0] + bL[r]);
  };
  auto compute = [&](int p){
    const unsigned short* A = &Abuf[p][0];
    const float* B = &Bbuf[p][0];
    short8 a[4], b[2];
#pragma unroll
    for (int mt = 0; mt < 4; mt++){
      int row = wm*64 + mt*16 + lrow;
      a[mt] = *(const short8*)(A + row*32 + ((quad ^ ((row>>1)&3)) * 8));
    }
#pragma unroll
    for (int nt = 0; nt < 2; nt++){
      int row = wn*32 + nt*16 + lrow;
      int g0 = (2*quad) ^ (row & 7), g1 = (2*quad+1) ^ (row & 7);
      float4 x = *(const float4*)(B + row*32 + g0*4);
      float4 y = *(const float4*)(B + row*32 + g1*4);
      b[nt] = cvt8(x, y);
    }
#pragma unroll
    for (int mt = 0; mt < 4; mt++)
#pragma unroll
      for (int nt = 0; nt < 2; nt++)
        acc[mt][nt] = __builtin_amdgcn_mfma_f32_16x16x32_bf16(a[mt], b[nt], acc[mt][nt], 0,0,0);
  };

  const int T = INTER / 32;   // 128
  issue(0, 0); issue(1, 1);
  for (int t = 0; t < T-1; t++){
    WAIT_BARRIER(4);
    compute(t & 1);
    RAW_BARRIER();
    if (t + 2 < T) issue(t + 2, t & 1);
  }
  WAIT_BARRIER(0);
  compute((T-1) & 1);

#pragma unroll
  for (int mt = 0; mt < 4; mt++){
#pragma unroll
    for (int reg = 0; reg < 4; reg++){
      int m = mtile*128 + wm*64 + mt*16 + quad*4 + reg;
      if (m >= cnt) continue;
      int tk  = tokl[base + m];
      float w = wtl[base + m];
#pragma unroll
      for (int nt = 0; nt < 2; nt++){
        int h = h0 + wn*32 + nt*16 + lrow;
        atomicAdd(&out[(size_t)tk * HID + h], w * acc[mt][nt][reg]);
      }
    }
  }
}

extern "C" void kernel_launch(void* const* d_in, const int* in_sizes, int n_in,
                              void* d_out, int out_size, void* d_ws, size_t ws_size,
                              hipStream_t stream){
  const float* hs  = (const float*)d_in[0];
  const int*   sel = (const int*)d_in[1];
  const float* rw  = (const float*)d_in[2];
  const float* w13 = (const float*)d_in[3];
  const float* w2  = (const float*)d_in[4];
  float* out = (float*)d_out;
  char* ws = (char*)d_ws;

  int* counts = (int*)ws;                      // 8
  int* bases  = counts + 8;                    // 8
  int* tokl   = bases + 8;                     // 512
  float* wtl  = (float*)(tokl + 512);          // 512
  // 640 rows (512 + 128 tile overrun pad); garbage rows are masked in epilogues
  unsigned short* hsg = (unsigned short*)(ws + 8192);            // 640*2048*2 = 2.5 MiB
  unsigned short* cur = (unsigned short*)(ws + 8192 + 640*HID*2);// 640*4096*2 = 5.0 MiB

  hipMemsetAsync(d_out, 0, (size_t)BT * HID * sizeof(float), stream);
  routing_kernel<<<1, 256, 0, stream>>>(sel, rw, counts, bases, tokl, wtl);
  gather_kernel<<<512, 256, 0, stream>>>(hs, counts, bases, tokl, hsg);
  dim3 g1(INTER/64, 2, NE);
  gemm1_kernel<<<g1, 256, 0, stream>>>(hsg, w13, counts, bases, cur);
  dim3 g2(HID/64, 2, NE);
  gemm2_kernel<<<g2, 256, 0, stream>>>(cur, w2, counts, bases, tokl, wtl, out);
}